// Round 1
// baseline (559.709 us; speedup 1.0000x reference)
//
#include <hip/hip_runtime.h>
#include <math.h>

// Color NGP: fused hash-grid encode (L=16, T=2^19, F=2, 4-D) + MLP 32->64->64->3
// One thread per point; layer-1 GEMV fused into the level loop so the encoding
// never materializes; weights staged in LDS (uniform broadcast reads).

#define NLEV 16
#define TSIZE (1u << 19)
#define TMASK (TSIZE - 1u)

__device__ __forceinline__ float gelu_exact(float x) {
    return 0.5f * x * (1.0f + erff(x * 0.70710678118654752440f));
}

__global__ __launch_bounds__(256) void ngp_fused(
    const float* __restrict__ inputs,   // [8,32768,3]
    const float* __restrict__ latent,   // [8,1]
    const float* __restrict__ table,    // [16, 2^19, 2]
    const float* __restrict__ W1, const float* __restrict__ b1,   // [32,64],[64]
    const float* __restrict__ W2, const float* __restrict__ b2,   // [64,64],[64]
    const float* __restrict__ W3, const float* __restrict__ b3,   // [64,3],[3]
    float* __restrict__ out)            // [8,32768,3]
{
    __shared__ __align__(16) float sW1[2048];
    __shared__ __align__(16) float sW2[4096];
    __shared__ __align__(16) float sW3[192];
    __shared__ float sb1[64];
    __shared__ float sb2[64];
    __shared__ float sb3[4];

    const int tid = threadIdx.x;
    #pragma unroll
    for (int i = 0; i < 8; ++i)  sW1[tid + 256 * i] = W1[tid + 256 * i];
    #pragma unroll
    for (int i = 0; i < 16; ++i) sW2[tid + 256 * i] = W2[tid + 256 * i];
    if (tid < 192) sW3[tid] = W3[tid];
    if (tid < 64) { sb1[tid] = b1[tid]; sb2[tid] = b2[tid]; }
    if (tid < 3)  sb3[tid] = b3[tid];

    const int p = blockIdx.x * 256 + tid;       // grid is exactly P/256
    const int bidx = p >> 15;                   // 32768 points per batch; block-uniform

    float x0 = inputs[p * 3 + 0];
    float x1 = inputs[p * 3 + 1];
    float x2 = inputs[p * 3 + 2];
    float x3 = latent[bidx];
    x0 = (x0 + 1.0f) * 0.5f;
    x1 = (x1 + 1.0f) * 0.5f;
    x2 = (x2 + 1.0f) * 0.5f;
    x3 = (x3 + 1.0f) * 0.5f;

    __syncthreads();

    // h1 pre-activation accumulator (bias added later)
    float h1[64];
    #pragma unroll
    for (int j = 0; j < 64; ++j) h1[j] = 0.0f;

    const float LOG2S = (float)log2(1.3819);    // matches np.float32(np.log2(1.3819))
    const float2* __restrict__ tab2 = (const float2*)table;

    #pragma unroll 2
    for (int l = 0; l < NLEV; ++l) {
        const float s = exp2f((float)l * LOG2S) * 16.0f - 1.0f;
        const float px = fmaf(x0, s, 0.5f);
        const float py = fmaf(x1, s, 0.5f);
        const float pz = fmaf(x2, s, 0.5f);
        const float pw = fmaf(x3, s, 0.5f);
        const float fx = floorf(px), fy = floorf(py), fz = floorf(pz), fw = floorf(pw);
        const float rx = px - fx, ry = py - fy, rz = pz - fz, rw = pw - fw;
        const int ix = (int)fx, iy = (int)fy, iz = (int)fz, iw = (int)fw;

        // Per-dim hash contributions (uint32 wraparound identical to numpy)
        const unsigned a0 = (unsigned)ix;                    const unsigned a1 = a0 + 1u;
        const unsigned b0 = (unsigned)iy * 2654435761u;      const unsigned b1v = b0 + 2654435761u;
        const unsigned c0 = (unsigned)iz * 805459861u;       const unsigned c1 = c0 + 805459861u;
        const unsigned d0 = (unsigned)iw * 3674653429u;      const unsigned d1 = d0 + 3674653429u;

        const float wx0 = 1.0f - rx, wy0 = 1.0f - ry, wz0 = 1.0f - rz, ww0 = 1.0f - rw;
        const float wxy[4] = { wx0 * wy0, rx * wy0, wx0 * ry, rx * ry };
        const float wzw[4] = { wz0 * ww0, rz * ww0, wz0 * rw, rz * rw };

        const unsigned base = (unsigned)l * TSIZE;
        float acc0 = 0.0f, acc1 = 0.0f;
        #pragma unroll
        for (int c = 0; c < 16; ++c) {
            unsigned h = ((c & 1) ? a1 : a0) ^ ((c & 2) ? b1v : b0)
                       ^ ((c & 4) ? c1 : c0) ^ ((c & 8) ? d1 : d0);
            const float2 v = tab2[base + (h & TMASK)];
            const float wgt = wxy[c & 3] * wzw[c >> 2];
            acc0 = fmaf(wgt, v.x, acc0);
            acc1 = fmaf(wgt, v.y, acc1);
        }

        // Fused layer-1 GEMV: h1 += acc0 * W1[2l,:] + acc1 * W1[2l+1,:]
        const float4* wr0 = (const float4*)&sW1[(2 * l    ) * 64];
        const float4* wr1 = (const float4*)&sW1[(2 * l + 1) * 64];
        #pragma unroll
        for (int j4 = 0; j4 < 16; ++j4) {
            const float4 wa = wr0[j4];
            const float4 wb = wr1[j4];
            h1[4 * j4 + 0] = fmaf(acc0, wa.x, fmaf(acc1, wb.x, h1[4 * j4 + 0]));
            h1[4 * j4 + 1] = fmaf(acc0, wa.y, fmaf(acc1, wb.y, h1[4 * j4 + 1]));
            h1[4 * j4 + 2] = fmaf(acc0, wa.z, fmaf(acc1, wb.z, h1[4 * j4 + 2]));
            h1[4 * j4 + 3] = fmaf(acc0, wa.w, fmaf(acc1, wb.w, h1[4 * j4 + 3]));
        }
    }

    // Bias + exact GELU for layer 1
    #pragma unroll
    for (int j = 0; j < 64; ++j) h1[j] = gelu_exact(h1[j] + sb1[j]);

    // Layer 2 (64->64) in chunks of 8 outputs, fused with layer 3 (64->3)
    float col0 = sb3[0], col1 = sb3[1], col2 = sb3[2];
    #pragma unroll 1
    for (int ch = 0; ch < 8; ++ch) {
        float acc[8];
        #pragma unroll
        for (int k = 0; k < 8; ++k) acc[k] = sb2[ch * 8 + k];
        #pragma unroll
        for (int i = 0; i < 64; ++i) {
            const float hv = h1[i];
            const float4* wr = (const float4*)&sW2[i * 64 + ch * 8];
            const float4 w0 = wr[0];
            const float4 w1 = wr[1];
            acc[0] = fmaf(hv, w0.x, acc[0]);
            acc[1] = fmaf(hv, w0.y, acc[1]);
            acc[2] = fmaf(hv, w0.z, acc[2]);
            acc[3] = fmaf(hv, w0.w, acc[3]);
            acc[4] = fmaf(hv, w1.x, acc[4]);
            acc[5] = fmaf(hv, w1.y, acc[5]);
            acc[6] = fmaf(hv, w1.z, acc[6]);
            acc[7] = fmaf(hv, w1.w, acc[7]);
        }
        #pragma unroll
        for (int k = 0; k < 8; ++k) {
            const float g = gelu_exact(acc[k]);
            const int j2 = ch * 8 + k;
            col0 = fmaf(g, sW3[j2 * 3 + 0], col0);
            col1 = fmaf(g, sW3[j2 * 3 + 1], col1);
            col2 = fmaf(g, sW3[j2 * 3 + 2], col2);
        }
    }

    out[p * 3 + 0] = col0;
    out[p * 3 + 1] = col1;
    out[p * 3 + 2] = col2;
}

extern "C" void kernel_launch(void* const* d_in, const int* in_sizes, int n_in,
                              void* d_out, int out_size, void* d_ws, size_t ws_size,
                              hipStream_t stream) {
    const float* inputs = (const float*)d_in[0];
    const float* latent = (const float*)d_in[1];
    const float* table  = (const float*)d_in[2];
    const float* W1 = (const float*)d_in[3];
    const float* b1 = (const float*)d_in[4];
    const float* W2 = (const float*)d_in[5];
    const float* b2 = (const float*)d_in[6];
    const float* W3 = (const float*)d_in[7];
    const float* b3 = (const float*)d_in[8];
    float* out = (float*)d_out;

    const int P = in_sizes[0] / 3;              // 262144
    ngp_fused<<<dim3(P / 256), dim3(256), 0, stream>>>(
        inputs, latent, table, W1, b1, W2, b2, W3, b3, out);
}